// Round 5
// baseline (646.263 us; speedup 1.0000x reference)
//
#include <hip/hip_runtime.h>
#include <math.h>

#define N_NODES 100000
#define N_EDGES 1600000
#define NEG 0.2f
#define MAXDEG 128
#define WPB 4   // waves per block for per-node kernels

__device__ __forceinline__ float lrelu(float x){ return x > 0.f ? x : NEG*x; }
__device__ __forceinline__ unsigned short f2bf(float f){
  unsigned int u = __float_as_uint(f);
  u += 0x7FFFu + ((u >> 16) & 1u);   // RNE
  return (unsigned short)(u >> 16);
}
// hardware XCD id (0..7 on MI355X) — wave-uniform
__device__ __forceinline__ unsigned xcc_id(){
  unsigned x;
  asm volatile("s_getreg_b32 %0, hwreg(HW_REG_XCC_ID)" : "=s"(x));
  return x & 7u;
}

// ---------------- degree count + rank + edge-attention dots ----------------
// R10: per-XCD private counters (all writers of deg8[xcc][*] are on XCD xcc).
// R11: that privatization makes WORKGROUP-scope atomics legal — device-scope
// RMWs are forced to the memory-side fabric on gfx950 (R10 evidence: XCD
// privatization alone left WRITE_SIZE at 68.65MB, identical to R9 — the 46MB
// excess is per-atomic EA traffic, not line bouncing). Workgroup scope drops
// the coherence bits so the RMW executes in the local TCC (L2), which every
// same-XCD workgroup shares -> atomicity holds; kernel-end release publishes.
__global__ __launch_bounds__(256) void k_deg(const int* __restrict__ dst, const float* __restrict__ eatt,
    const float* __restrict__ We0, const float* __restrict__ ae0,
    const float* __restrict__ We1, const float* __restrict__ ae1,
    int* __restrict__ deg8, int* __restrict__ rank, float2* __restrict__ ae01){
  __shared__ float wea[32];
  int t = threadIdx.x;
  if (t < 32){
    const float* W = (t < 16) ? We0 : We1;
    const float* a = (t < 16) ? ae0 : ae1;
    int r = t & 15;
    float acc = 0.f;
    #pragma unroll
    for (int j=0;j<128;j++) acc += W[r*128+j]*a[j];
    wea[t] = acc;
  }
  __syncthreads();
  unsigned xcc = xcc_id();
  int* mydeg = deg8 + (size_t)xcc * N_NODES;
  int e = blockIdx.x*256 + t;
  if (e >= N_EDGES) return;
  const float4* p = (const float4*)(eatt + (size_t)e*16);
  float4 a0=p[0], a1=p[1], a2=p[2], a3=p[3];
  // identical association order to the R6 dot -> bit-exact
  float f0 = a0.x*wea[0] +a0.y*wea[1] +a0.z*wea[2] +a0.w*wea[3]
           + a1.x*wea[4] +a1.y*wea[5] +a1.z*wea[6] +a1.w*wea[7]
           + a2.x*wea[8] +a2.y*wea[9] +a2.z*wea[10]+a2.w*wea[11]
           + a3.x*wea[12]+a3.y*wea[13]+a3.z*wea[14]+a3.w*wea[15];
  float f1 = a0.x*wea[16]+a0.y*wea[17]+a0.z*wea[18]+a0.w*wea[19]
           + a1.x*wea[20]+a1.y*wea[21]+a1.z*wea[22]+a1.w*wea[23]
           + a2.x*wea[24]+a2.y*wea[25]+a2.z*wea[26]+a2.w*wea[27]
           + a3.x*wea[28]+a3.y*wea[29]+a3.z*wea[30]+a3.w*wea[31];
  int r = __hip_atomic_fetch_add(&mydeg[dst[e]], 1,
                                 __ATOMIC_RELAXED, __HIP_MEMORY_SCOPE_WORKGROUP);
  rank[e] = r | (int)(xcc << 24);
  ae01[e] = make_float2(f0, f1);
}

// ---------------- exclusive scan (3 phase) ----------------
// scan_a sums the 8 XCD replicas into deg[] and scans the totals.
__global__ __launch_bounds__(256) void k_scan_a(const int* __restrict__ deg8, int* __restrict__ deg,
    int* __restrict__ incl, int* __restrict__ bsum){
  __shared__ int s[256];
  int t = threadIdx.x; int i = blockIdx.x*256 + t;
  int v = 0;
  if (i < N_NODES){
    #pragma unroll
    for (int x=0;x<8;x++) v += deg8[(size_t)x*N_NODES + i];
    deg[i] = v;
  }
  s[t] = v; __syncthreads();
  for (int off=1; off<256; off<<=1){
    int u = (t>=off)? s[t-off] : 0; __syncthreads();
    s[t] += u; __syncthreads();
  }
  if (i < N_NODES) incl[i] = s[t];
  if (t == 255) bsum[blockIdx.x] = s[t];
}
__global__ __launch_bounds__(512) void k_scan_b(const int* __restrict__ bsum, int* __restrict__ bexcl, int nb){
  __shared__ int s[512];
  int t = threadIdx.x;
  int v = (t<nb)? bsum[t] : 0;
  s[t] = v; __syncthreads();
  for (int off=1; off<512; off<<=1){
    int u = (t>=off)? s[t-off] : 0; __syncthreads();
    s[t] += u; __syncthreads();
  }
  if (t<nb) bexcl[t] = s[t]-v;
}
// scan_c emits rowptr (for k_agg) and per-XCD absolute bases rowptr8
// (for k_fillf: pos = rowptr8[d*8+xcc] + local rank, one gather as before).
__global__ __launch_bounds__(256) void k_scan_c(const int* __restrict__ incl, const int* __restrict__ deg,
    const int* __restrict__ bexcl, const int* __restrict__ deg8,
    int* __restrict__ rowptr, int* __restrict__ rowptr8){
  int i = blockIdx.x*256+threadIdx.x;
  if (i < N_NODES){
    int base = incl[i] - deg[i] + bexcl[blockIdx.x];
    rowptr[i] = base;
    int run = base;
    #pragma unroll
    for (int x=0;x<8;x++){
      rowptr8[(size_t)i*8 + x] = run;
      run += deg8[(size_t)x*N_NODES + i];
    }
  }
  if (i == 0) rowptr[N_NODES] = N_EDGES;
}

// ---------------- CSR fill: pure gather -> scatter ----------------
__global__ __launch_bounds__(256) void k_fillf(const int* __restrict__ src, const int* __restrict__ dst,
     const int* __restrict__ rank, const float2* __restrict__ ae01,
     const int* __restrict__ rowptr8, uint4* __restrict__ csr){
  int e = blockIdx.x*256+threadIdx.x;
  if (e >= N_EDGES) return;
  int d = dst[e];
  unsigned rk = (unsigned)rank[e];
  float2 ae = ae01[e];
  int pos = rowptr8[(size_t)d*8 + (rk >> 24)] + (int)(rk & 0xFFFFFFu);
  csr[pos] = make_uint4((unsigned)src[e], __float_as_uint(ae.x), __float_as_uint(ae.y), 0u);
}

// ---------------- fp32 GEMM + optional fused attention dots ----------------
__global__ __launch_bounds__(256) void k_gemm(const float* __restrict__ X, const float* __restrict__ W,
    const float* __restrict__ bias, float* __restrict__ Y, unsigned short* __restrict__ Ybf,
    const float* __restrict__ a_s, const float* __restrict__ a_d,
    float* __restrict__ asrc, float* __restrict__ adst, int M, int relu){
  __shared__ float Xs[16][68];
  __shared__ float Ws[16][128];
  __shared__ float as_s[128], ad_s[128];
  int t = threadIdx.x;
  if (a_s && t < 128){ as_s[t] = a_s[t]; ad_s[t] = a_d[t]; }
  int row0 = blockIdx.x * 64;
  int tc = t & 15, tr = t >> 4;
  int c0 = tc*8, r0 = tr*4;
  int lr = t >> 2, lc = (t & 3) << 2;
  int wk = t >> 4, wc = (t & 15) * 8;
  float acc[4][8];
  #pragma unroll
  for (int i=0;i<4;i++)
    #pragma unroll
    for (int j=0;j<8;j++) acc[i][j]=0.f;
  int gr = row0 + lr;
  for (int k0=0; k0<128; k0+=16){
    float4 xv = make_float4(0.f,0.f,0.f,0.f);
    if (gr < M) xv = *(const float4*)(X + (size_t)gr*128 + k0 + lc);
    float4 wv0 = *(const float4*)(W + (size_t)(k0+wk)*128 + wc);
    float4 wv1 = *(const float4*)(W + (size_t)(k0+wk)*128 + wc + 4);
    __syncthreads();
    Xs[lc+0][lr]=xv.x; Xs[lc+1][lr]=xv.y; Xs[lc+2][lr]=xv.z; Xs[lc+3][lr]=xv.w;
    *(float4*)&Ws[wk][wc]   = wv0;
    *(float4*)&Ws[wk][wc+4] = wv1;
    __syncthreads();
    #pragma unroll
    for (int kk=0;kk<16;kk++){
      float4 a  = *(const float4*)&Xs[kk][r0];
      float4 b0 = *(const float4*)&Ws[kk][c0];
      float4 b1 = *(const float4*)&Ws[kk][c0+4];
      float av[4] = {a.x,a.y,a.z,a.w};
      float bv[8] = {b0.x,b0.y,b0.z,b0.w,b1.x,b1.y,b1.z,b1.w};
      #pragma unroll
      for (int i=0;i<4;i++)
        #pragma unroll
        for (int j=0;j<8;j++) acc[i][j] += av[i]*bv[j];
    }
  }
  #pragma unroll
  for (int i=0;i<4;i++){
    int r = row0 + r0 + i;
    float v[8];
    #pragma unroll
    for (int j=0;j<8;j++){
      float u = acc[i][j] + (bias ? bias[c0+j] : 0.f);
      v[j] = relu ? fmaxf(u, 0.f) : u;
    }
    if (r < M){
      if (Y){
        *(float4*)(Y + (size_t)r*128 + c0)     = make_float4(v[0],v[1],v[2],v[3]);
        *(float4*)(Y + (size_t)r*128 + c0 + 4) = make_float4(v[4],v[5],v[6],v[7]);
      }
      if (Ybf){
        uint4 pk;
        pk.x = (unsigned)f2bf(v[0]) | ((unsigned)f2bf(v[1])<<16);
        pk.y = (unsigned)f2bf(v[2]) | ((unsigned)f2bf(v[3])<<16);
        pk.z = (unsigned)f2bf(v[4]) | ((unsigned)f2bf(v[5])<<16);
        pk.w = (unsigned)f2bf(v[6]) | ((unsigned)f2bf(v[7])<<16);
        *(uint4*)(Ybf + (size_t)r*128 + c0) = pk;
      }
    }
    if (a_s){
      float s=0.f, d=0.f;
      #pragma unroll
      for (int j=0;j<8;j++){ s += v[j]*as_s[c0+j]; d += v[j]*ad_s[c0+j]; }
      #pragma unroll
      for (int off=1; off<16; off<<=1){ s += __shfl_xor(s,off); d += __shfl_xor(d,off); }
      if ((t & 15)==0 && r < M){ asrc[r]=s; adst[r]=d; }
    }
  }
}

// ---------------- GAT aggregation: wave per node ----------------
// R11: pass C main body x4 — four independent row gathers in flight per
// wave (still latency-limited at x2: 59% VALU / 40% HBM). Per-slot FMA
// sequence unchanged (g, g+4, g+8, g+12, ...) -> bit-exact.
__global__ __launch_bounds__(256) void k_agg(const int* __restrict__ rowptr, const uint4* __restrict__ csr,
    const float* __restrict__ asrc, const float* __restrict__ adst,
    const unsigned short* __restrict__ xlbf,
    const float* __restrict__ bias, float* __restrict__ out, int relu, int layer){
  int w = threadIdx.x >> 6;
  int lane = threadIdx.x & 63;
  int n = blockIdx.x * WPB + w;          // grid exact
  __shared__ float2 eb[WPB][MAXDEG];     // {alpha->weight, byteoff bits}
  const char* xbase = (const char*)xlbf; // row = 256 B
  int s0 = rowptr[n], s1 = rowptr[n+1];
  int deg = s1 - s0;
  float adst_n = adst[n];
  // pass A
  float m_edge = -1e30f;
  float sae = 0.f;
  for (int base=0; base<deg; base+=64){
    int i = base + lane;
    float a = -1e30f;
    if (i < deg){
      uint4 p4 = csr[s0 + i];
      int sx = (int)p4.x;
      float ae = __uint_as_float(layer ? p4.z : p4.y);
      float av = lrelu(asrc[sx] + adst_n + ae);
      if (i < MAXDEG) eb[w][i] = make_float2(av, __uint_as_float((unsigned)sx << 8));
      a = av;
      sae += ae;
    }
    for (int off=32; off; off>>=1) a = fmaxf(a, __shfl_xor(a, off));
    m_edge = fmaxf(m_edge, a);
  }
  for (int off=32; off; off>>=1) sae += __shfl_xor(sae, off);
  float aloop_n = sae / fmaxf((float)deg, 1.f);
  float al = lrelu(asrc[n] + adst_n + aloop_n);   // self-loop alpha
  float m = fmaxf(m_edge, al);
  // pass B
  float p = 0.f;
  for (int i=lane; i<deg; i+=64){
    float av;
    if (i < MAXDEG) av = eb[w][i].x;
    else { uint4 p4 = csr[s0+i];
           av = lrelu(asrc[p4.x] + adst_n + __uint_as_float(layer ? p4.z : p4.y)); }
    float ev = __expf(av - m);
    if (i < MAXDEG) eb[w][i].x = ev;
    p += ev;
  }
  for (int off=32; off; off>>=1) p += __shfl_xor(p, off);
  float wl = __expf(al - m);
  float denom = p + wl;
  __syncthreads();
  // pass C
  int g = lane >> 4, cl = lane & 15;
  unsigned clb = (unsigned)(cl << 4);
  float acc[8];
  #pragma unroll
  for (int j=0;j<8;j++) acc[j]=0.f;
  if (g == 0){
    uint4 v = *(const uint4*)(xbase + (((unsigned)n << 8) + clb));
    unsigned int uu[4] = {v.x,v.y,v.z,v.w};
    #pragma unroll
    for (int q=0;q<4;q++){
      acc[2*q]   += wl * __uint_as_float(uu[q] << 16);
      acc[2*q+1] += wl * __uint_as_float(uu[q] & 0xFFFF0000u);
    }
  }
  if (deg <= MAXDEG){
    int dfull16 = deg & ~15;
    for (int i=0; i<dfull16; i+=16){   // unguarded x4 body
      float2 e0 = eb[w][i+g];
      float2 e1 = eb[w][i+4+g];
      float2 e2 = eb[w][i+8+g];
      float2 e3 = eb[w][i+12+g];
      uint4 v0 = *(const uint4*)(xbase + (__float_as_uint(e0.y) + clb));
      uint4 v1 = *(const uint4*)(xbase + (__float_as_uint(e1.y) + clb));
      uint4 v2 = *(const uint4*)(xbase + (__float_as_uint(e2.y) + clb));
      uint4 v3 = *(const uint4*)(xbase + (__float_as_uint(e3.y) + clb));
      unsigned int uu0[4] = {v0.x,v0.y,v0.z,v0.w};
      unsigned int uu1[4] = {v1.x,v1.y,v1.z,v1.w};
      unsigned int uu2[4] = {v2.x,v2.y,v2.z,v2.w};
      unsigned int uu3[4] = {v3.x,v3.y,v3.z,v3.w};
      #pragma unroll
      for (int q=0;q<4;q++){
        acc[2*q]   += e0.x * __uint_as_float(uu0[q] << 16);
        acc[2*q+1] += e0.x * __uint_as_float(uu0[q] & 0xFFFF0000u);
      }
      #pragma unroll
      for (int q=0;q<4;q++){
        acc[2*q]   += e1.x * __uint_as_float(uu1[q] << 16);
        acc[2*q+1] += e1.x * __uint_as_float(uu1[q] & 0xFFFF0000u);
      }
      #pragma unroll
      for (int q=0;q<4;q++){
        acc[2*q]   += e2.x * __uint_as_float(uu2[q] << 16);
        acc[2*q+1] += e2.x * __uint_as_float(uu2[q] & 0xFFFF0000u);
      }
      #pragma unroll
      for (int q=0;q<4;q++){
        acc[2*q]   += e3.x * __uint_as_float(uu3[q] << 16);
        acc[2*q+1] += e3.x * __uint_as_float(uu3[q] & 0xFFFF0000u);
      }
    }
    int dfull8 = deg & ~7;
    for (int i=dfull16; i<dfull8; i+=8){   // x2 remainder (0 or 1 iter)
      float2 e0 = eb[w][i+g];
      float2 e1 = eb[w][i+4+g];
      uint4 v0 = *(const uint4*)(xbase + (__float_as_uint(e0.y) + clb));
      uint4 v1 = *(const uint4*)(xbase + (__float_as_uint(e1.y) + clb));
      unsigned int uu0[4] = {v0.x,v0.y,v0.z,v0.w};
      unsigned int uu1[4] = {v1.x,v1.y,v1.z,v1.w};
      #pragma unroll
      for (int q=0;q<4;q++){
        acc[2*q]   += e0.x * __uint_as_float(uu0[q] << 16);
        acc[2*q+1] += e0.x * __uint_as_float(uu0[q] & 0xFFFF0000u);
      }
      #pragma unroll
      for (int q=0;q<4;q++){
        acc[2*q]   += e1.x * __uint_as_float(uu1[q] << 16);
        acc[2*q+1] += e1.x * __uint_as_float(uu1[q] & 0xFFFF0000u);
      }
    }
    for (int i=dfull8; i<deg; i+=4){    // guarded tail (<8 edges)
      int idx = i + g;
      float we = 0.f; unsigned off = (unsigned)n << 8;
      if (idx < deg){ float2 e = eb[w][idx]; we = e.x; off = __float_as_uint(e.y); }
      uint4 v = *(const uint4*)(xbase + (off + clb));
      unsigned int uu[4] = {v.x,v.y,v.z,v.w};
      #pragma unroll
      for (int q=0;q<4;q++){
        acc[2*q]   += we * __uint_as_float(uu[q] << 16);
        acc[2*q+1] += we * __uint_as_float(uu[q] & 0xFFFF0000u);
      }
    }
  } else {
    for (int i=0; i<deg; i+=8){
      int idx0 = i + g, idx1 = i + 4 + g;
      int sx0 = n, sx1 = n; float we0 = 0.f, we1 = 0.f;
      if (idx0 < deg){
        if (idx0 < MAXDEG){ float2 e = eb[w][idx0]; we0 = e.x; sx0 = (int)(__float_as_uint(e.y) >> 8); }
        else { uint4 p4 = csr[s0+idx0]; sx0 = (int)p4.x;
               we0 = __expf(lrelu(asrc[sx0] + adst_n + __uint_as_float(layer ? p4.z : p4.y)) - m); }
      }
      if (idx1 < deg){
        if (idx1 < MAXDEG){ float2 e = eb[w][idx1]; we1 = e.x; sx1 = (int)(__float_as_uint(e.y) >> 8); }
        else { uint4 p4 = csr[s0+idx1]; sx1 = (int)p4.x;
               we1 = __expf(lrelu(asrc[sx1] + adst_n + __uint_as_float(layer ? p4.z : p4.y)) - m); }
      }
      uint4 v0 = *(const uint4*)(xbase + (((unsigned)sx0 << 8) + clb));
      uint4 v1 = *(const uint4*)(xbase + (((unsigned)sx1 << 8) + clb));
      unsigned int uu0[4] = {v0.x,v0.y,v0.z,v0.w};
      unsigned int uu1[4] = {v1.x,v1.y,v1.z,v1.w};
      #pragma unroll
      for (int q=0;q<4;q++){
        acc[2*q]   += we0 * __uint_as_float(uu0[q] << 16);
        acc[2*q+1] += we0 * __uint_as_float(uu0[q] & 0xFFFF0000u);
      }
      #pragma unroll
      for (int q=0;q<4;q++){
        acc[2*q]   += we1 * __uint_as_float(uu1[q] << 16);
        acc[2*q+1] += we1 * __uint_as_float(uu1[q] & 0xFFFF0000u);
      }
    }
  }
  #pragma unroll
  for (int j=0;j<8;j++){
    acc[j] += __shfl_xor(acc[j], 16);
    acc[j] += __shfl_xor(acc[j], 32);
  }
  if (lane < 16){
    float inv = 1.f/denom;
    float4 b0 = *(const float4*)(bias + cl*8);
    float4 b1 = *(const float4*)(bias + cl*8 + 4);
    float o[8];
    o[0]=acc[0]*inv+b0.x; o[1]=acc[1]*inv+b0.y; o[2]=acc[2]*inv+b0.z; o[3]=acc[3]*inv+b0.w;
    o[4]=acc[4]*inv+b1.x; o[5]=acc[5]*inv+b1.y; o[6]=acc[6]*inv+b1.z; o[7]=acc[7]*inv+b1.w;
    if (relu){
      #pragma unroll
      for (int j=0;j<8;j++) o[j]=fmaxf(o[j],0.f);
    }
    *(float4*)(out + (size_t)n*128 + cl*8)     = make_float4(o[0],o[1],o[2],o[3]);
    *(float4*)(out + (size_t)n*128 + cl*8 + 4) = make_float4(o[4],o[5],o[6],o[7]);
  }
}

// ---------------- fused MLP: lin1 GEMM -> lin2 -> log_softmax ----------------
// R10: h in registers, lin2 via 16-lane ring-rotate (LDS 12.6KB; was 46.6KB
// at 17.5% occupancy with 8M bank conflicts). Verified: left top-5.
__global__ __launch_bounds__(256) void k_mlp(const float* __restrict__ X, const float* __restrict__ W,
    const float* __restrict__ bias, const float* __restrict__ w2, const float* __restrict__ b2,
    float* __restrict__ out, int M){
  __shared__ float Xs[16][68];
  __shared__ float Ws[16][128];
  __shared__ float b2s[16];
  int t = threadIdx.x;
  int row0 = blockIdx.x * 64;
  int tc = t & 15, tr = t >> 4;
  int c0 = tc*8, r0 = tr*4;
  int lr = t >> 2, lc = (t & 3) << 2;
  int wk = t >> 4, wc = (t & 15) * 8;
  float acc[4][8];
  #pragma unroll
  for (int i=0;i<4;i++)
    #pragma unroll
    for (int j=0;j<8;j++) acc[i][j]=0.f;
  int gr = row0 + lr;
  for (int k0=0; k0<128; k0+=16){
    float4 xv = make_float4(0.f,0.f,0.f,0.f);
    if (gr < M) xv = *(const float4*)(X + (size_t)gr*128 + k0 + lc);
    float4 wv0 = *(const float4*)(W + (size_t)(k0+wk)*128 + wc);
    float4 wv1 = *(const float4*)(W + (size_t)(k0+wk)*128 + wc + 4);
    __syncthreads();
    Xs[lc+0][lr]=xv.x; Xs[lc+1][lr]=xv.y; Xs[lc+2][lr]=xv.z; Xs[lc+3][lr]=xv.w;
    *(float4*)&Ws[wk][wc]   = wv0;
    *(float4*)&Ws[wk][wc+4] = wv1;
    __syncthreads();
    #pragma unroll
    for (int kk=0;kk<16;kk++){
      float4 a  = *(const float4*)&Xs[kk][r0];
      float4 b0 = *(const float4*)&Ws[kk][c0];
      float4 b1 = *(const float4*)&Ws[kk][c0+4];
      float av[4] = {a.x,a.y,a.z,a.w};
      float bv[8] = {b0.x,b0.y,b0.z,b0.w,b1.x,b1.y,b1.z,b1.w};
      #pragma unroll
      for (int i=0;i<4;i++)
        #pragma unroll
        for (int j=0;j<8;j++) acc[i][j] += av[i]*bv[j];
    }
  }
  __syncthreads();   // all Ws reads done before restage
  float* wflat = &Ws[0][0];   // w2 restaged here: wflat[col*16 + cls]
  #pragma unroll
  for (int i=0;i<2;i++) ((float4*)wflat)[t + i*256] = ((const float4*)w2)[t + i*256];
  if (t < 16) b2s[t] = b2[t];
  // h = relu(acc + l1b) in registers
  float4 bba = *(const float4*)(bias + c0);
  float4 bbb = *(const float4*)(bias + c0 + 4);
  float bb[8] = {bba.x,bba.y,bba.z,bba.w,bbb.x,bbb.y,bbb.z,bbb.w};
  #pragma unroll
  for (int i=0;i<4;i++)
    #pragma unroll
    for (int j=0;j<8;j++) acc[i][j] = fmaxf(acc[i][j] + bb[j], 0.f);
  __syncthreads();   // w2/b2 staged
  // ring-rotate lin2: conflict-free w2 reads (banks j*16+cls, cls distinct)
  float A0=0.f, A1=0.f, A2=0.f, A3=0.f;
  int sl = (tc+1) & 15;
  #pragma unroll 4
  for (int s=0; s<16; s++){
    int cls = (tc + s) & 15;
    const float* wp = wflat + (size_t)c0*16 + cls;
    float p0=0.f,p1=0.f,p2=0.f,p3=0.f;
    #pragma unroll
    for (int j=0;j<8;j++){
      float wv = wp[j*16];
      p0 += acc[0][j]*wv; p1 += acc[1][j]*wv; p2 += acc[2][j]*wv; p3 += acc[3][j]*wv;
    }
    A0+=p0; A1+=p1; A2+=p2; A3+=p3;
    A0=__shfl(A0,sl,16); A1=__shfl(A1,sl,16); A2=__shfl(A2,sl,16); A3=__shfl(A3,sl,16);
  }
  float A[4] = {A0,A1,A2,A3};
  float bcls = b2s[tc];
  #pragma unroll
  for (int i=0;i<4;i++){
    float v = A[i] + bcls;
    float m = v;
    #pragma unroll
    for (int off=1; off<16; off<<=1) m = fmaxf(m, __shfl_xor(m, off, 16));
    float ex = __expf(v - m);
    float sum = ex;
    #pragma unroll
    for (int off=1; off<16; off<<=1) sum += __shfl_xor(sum, off, 16);
    float lse = m + __logf(sum);
    int r = row0 + r0 + i;
    if (r < M) out[(size_t)r*16 + tc] = v - lse;
  }
}

extern "C" void kernel_launch(void* const* d_in, const int* in_sizes, int n_in,
                              void* d_out, int out_size, void* d_ws, size_t ws_size,
                              hipStream_t stream){
  const float* x    = (const float*)d_in[0];
  const float* eatt = (const float*)d_in[1];
  const float* W0   = (const float*)d_in[2];
  const float* as0  = (const float*)d_in[3];
  const float* ad0  = (const float*)d_in[4];
  const float* We0  = (const float*)d_in[5];
  const float* ae0  = (const float*)d_in[6];
  const float* b0   = (const float*)d_in[7];
  const float* W1   = (const float*)d_in[8];
  const float* as1  = (const float*)d_in[9];
  const float* ad1  = (const float*)d_in[10];
  const float* We1  = (const float*)d_in[11];
  const float* ae1  = (const float*)d_in[12];
  const float* b1   = (const float*)d_in[13];
  const float* l1w  = (const float*)d_in[14];
  const float* l1b  = (const float*)d_in[15];
  const float* l2w  = (const float*)d_in[16];
  const float* l2b  = (const float*)d_in[17];
  const int*   ei   = (const int*)d_in[18];
  const int* srcI = ei;
  const int* dstI = ei + N_EDGES;
  float* out = (float*)d_out;

  char* p = (char*)d_ws;
  auto alloc = [&](size_t bytes)->char*{ char* r = p; p += (bytes + 255) & ~255ull; return r; };
  unsigned short* Abf = (unsigned short*)alloc((size_t)N_NODES*128*2); // bf16 features
  float* B       = (float*)alloc((size_t)N_NODES*128*4);   // aggregation output
  float* asrc    = (float*)alloc((size_t)N_NODES*4);
  float* adst    = (float*)alloc((size_t)N_NODES*4);
  int* deg     = (int*)alloc((size_t)N_NODES*4);
  int* rowptr  = (int*)alloc((size_t)(N_NODES+1)*4);
  uint4* csr   = (uint4*)alloc((size_t)N_EDGES*16);
  int* incl    = (int*)alloc((size_t)N_NODES*4);
  int* bsum    = (int*)alloc(512*4);
  int* bexcl   = (int*)alloc(512*4);
  // preprocessing-only buffers live in regions that are dead until the
  // GEMM/agg phase (no extra workspace):
  float2* ae01   = (float2*)Abf;                       // 12.8MB <= 25.6MB
  char*   Bc     = (char*)B;                           // 51.2MB region
  int*    rank   = (int*)Bc;                           // 6.4MB  (dead before k_agg writes B)
  int*    deg8   = (int*)(Bc + 6400000);               // 3.2MB  8x per-XCD counters
  int*    rowptr8= (int*)(Bc + 6400000 + 3200000);     // 3.2MB  per-XCD absolute bases

  const int NB_E = (N_EDGES+255)/256;   // 6250
  const int NB_N = (N_NODES+255)/256;   // 391
  const int NB_W = N_NODES/WPB;         // 25000 (exact)
  const int NB_G = (N_NODES+63)/64;     // 1563

  // ---- shared preprocessing ----
  hipMemsetAsync(deg8, 0, (size_t)8*N_NODES*4, stream);
  k_deg   <<<NB_E,256,0,stream>>>(dstI, eatt, We0, ae0, We1, ae1, deg8, rank, ae01);
  k_scan_a<<<NB_N,256,0,stream>>>(deg8, deg, incl, bsum);
  k_scan_b<<<1,  512,0,stream>>>(bsum, bexcl, NB_N);
  k_scan_c<<<NB_N,256,0,stream>>>(incl, deg, bexcl, deg8, rowptr, rowptr8);
  k_fillf <<<NB_E,256,0,stream>>>(srcI, dstI, rank, ae01, rowptr8, csr);

  // ---- layer 0 ----
  k_gemm <<<NB_G,256,0,stream>>>(x, W0, nullptr, nullptr, Abf, as0, ad0, asrc, adst, N_NODES, 0);
  k_agg  <<<NB_W,256,0,stream>>>(rowptr, csr, asrc, adst, Abf, b0, B, 1, 0);

  // ---- layer 1 ----
  k_gemm <<<NB_G,256,0,stream>>>(B, W1, nullptr, nullptr, Abf, as1, ad1, asrc, adst, N_NODES, 0);
  k_agg  <<<NB_W,256,0,stream>>>(rowptr, csr, asrc, adst, Abf, b1, B, 1, 1);

  // ---- post MLP (lin1 + lin2 + log_softmax fused) ----
  k_mlp  <<<NB_G,256,0,stream>>>(B, l1w, l1b, l2w, l2b, out, N_NODES);
}

// Round 6
// 602.140 us; speedup vs baseline: 1.0733x; 1.0733x over previous
//
#include <hip/hip_runtime.h>
#include <math.h>

#define N_NODES 100000
#define N_EDGES 1600000
#define NEG 0.2f
#define MAXDEG 128
#define WPB 4   // waves per block for per-node kernels

__device__ __forceinline__ float lrelu(float x){ return x > 0.f ? x : NEG*x; }
__device__ __forceinline__ unsigned short f2bf(float f){
  unsigned int u = __float_as_uint(f);
  u += 0x7FFFu + ((u >> 16) & 1u);   // RNE
  return (unsigned short)(u >> 16);
}

// ---------------- fused preprocessing + layer-0 GEMM ----------------
// R12: k_deg is atomic-latency-bound (84us at 4% VALU / 19% HBM; R10/R11
// proved the 1.6M random RMWs run at a fixed memory-side rate regardless of
// scope/privatization). The layer-0 GEMM is independent of preprocessing —
// interleave both as block roles in ONE dispatch (every 5th block = GEMM,
// matching 6250:1563) so the GEMM consumes the VALU/HBM the deg blocks
// leave idle. deg8/rowptr8 reverted (measured null, R10/R11).
__global__ __launch_bounds__(256) void k_pre(const int* __restrict__ dst, const float* __restrict__ eatt,
    const float* __restrict__ We0, const float* __restrict__ ae0,
    const float* __restrict__ We1, const float* __restrict__ ae1,
    int* __restrict__ deg, int* __restrict__ rank, float2* __restrict__ ae01,
    const float* __restrict__ X, const float* __restrict__ W,
    const float* __restrict__ a_s, const float* __restrict__ a_d,
    unsigned short* __restrict__ Ybf, float* __restrict__ asrc, float* __restrict__ adst){
  __shared__ float Xs[16][68];
  __shared__ float Ws[16][128];
  __shared__ float as_s[128], ad_s[128];
  int t = threadIdx.x;
  int bid = blockIdx.x;
  int rem = bid % 5;
  if (rem != 4){
    // ---- deg role: edge block (bid/5)*4 + rem ----
    float* wea = &Ws[0][0];   // 32 floats staged in shared
    if (t < 32){
      const float* Wm = (t < 16) ? We0 : We1;
      const float* am = (t < 16) ? ae0 : ae1;
      int r = t & 15;
      float acc = 0.f;
      #pragma unroll
      for (int j=0;j<128;j++) acc += Wm[r*128+j]*am[j];
      wea[t] = acc;
    }
    __syncthreads();
    int e = ((bid/5)*4 + rem)*256 + t;
    if (e >= N_EDGES) return;
    const float4* p = (const float4*)(eatt + (size_t)e*16);
    float4 a0=p[0], a1=p[1], a2=p[2], a3=p[3];
    // identical association order to the R6 dot -> bit-exact
    float f0 = a0.x*wea[0] +a0.y*wea[1] +a0.z*wea[2] +a0.w*wea[3]
             + a1.x*wea[4] +a1.y*wea[5] +a1.z*wea[6] +a1.w*wea[7]
             + a2.x*wea[8] +a2.y*wea[9] +a2.z*wea[10]+a2.w*wea[11]
             + a3.x*wea[12]+a3.y*wea[13]+a3.z*wea[14]+a3.w*wea[15];
    float f1 = a0.x*wea[16]+a0.y*wea[17]+a0.z*wea[18]+a0.w*wea[19]
             + a1.x*wea[20]+a1.y*wea[21]+a1.z*wea[22]+a1.w*wea[23]
             + a2.x*wea[24]+a2.y*wea[25]+a2.z*wea[26]+a2.w*wea[27]
             + a3.x*wea[28]+a3.y*wea[29]+a3.z*wea[30]+a3.w*wea[31];
    rank[e] = atomicAdd(&deg[dst[e]], 1);
    ae01[e] = make_float2(f0, f1);
    return;
  }
  // ---- GEMM role: x@W0 -> Abf(bf16) + asrc/adst, tile (bid/5) ----
  if (t < 128){ as_s[t] = a_s[t]; ad_s[t] = a_d[t]; }
  int row0 = (bid/5) * 64;
  int tc = t & 15, tr = t >> 4;
  int c0 = tc*8, r0 = tr*4;
  int lr = t >> 2, lc = (t & 3) << 2;
  int wk = t >> 4, wc = (t & 15) * 8;
  float acc[4][8];
  #pragma unroll
  for (int i=0;i<4;i++)
    #pragma unroll
    for (int j=0;j<8;j++) acc[i][j]=0.f;
  int gr = row0 + lr;
  for (int k0=0; k0<128; k0+=16){
    float4 xv = make_float4(0.f,0.f,0.f,0.f);
    if (gr < N_NODES) xv = *(const float4*)(X + (size_t)gr*128 + k0 + lc);
    float4 wv0 = *(const float4*)(W + (size_t)(k0+wk)*128 + wc);
    float4 wv1 = *(const float4*)(W + (size_t)(k0+wk)*128 + wc + 4);
    __syncthreads();
    Xs[lc+0][lr]=xv.x; Xs[lc+1][lr]=xv.y; Xs[lc+2][lr]=xv.z; Xs[lc+3][lr]=xv.w;
    *(float4*)&Ws[wk][wc]   = wv0;
    *(float4*)&Ws[wk][wc+4] = wv1;
    __syncthreads();
    #pragma unroll
    for (int kk=0;kk<16;kk++){
      float4 a  = *(const float4*)&Xs[kk][r0];
      float4 b0 = *(const float4*)&Ws[kk][c0];
      float4 b1 = *(const float4*)&Ws[kk][c0+4];
      float av[4] = {a.x,a.y,a.z,a.w};
      float bv[8] = {b0.x,b0.y,b0.z,b0.w,b1.x,b1.y,b1.z,b1.w};
      #pragma unroll
      for (int i=0;i<4;i++)
        #pragma unroll
        for (int j=0;j<8;j++) acc[i][j] += av[i]*bv[j];
    }
  }
  #pragma unroll
  for (int i=0;i<4;i++){
    int r = row0 + r0 + i;
    float v[8];
    #pragma unroll
    for (int j=0;j<8;j++) v[j] = acc[i][j];
    if (r < N_NODES){
      uint4 pk;
      pk.x = (unsigned)f2bf(v[0]) | ((unsigned)f2bf(v[1])<<16);
      pk.y = (unsigned)f2bf(v[2]) | ((unsigned)f2bf(v[3])<<16);
      pk.z = (unsigned)f2bf(v[4]) | ((unsigned)f2bf(v[5])<<16);
      pk.w = (unsigned)f2bf(v[6]) | ((unsigned)f2bf(v[7])<<16);
      *(uint4*)(Ybf + (size_t)r*128 + c0) = pk;
    }
    float s=0.f, d=0.f;
    #pragma unroll
    for (int j=0;j<8;j++){ s += v[j]*as_s[c0+j]; d += v[j]*ad_s[c0+j]; }
    #pragma unroll
    for (int off=1; off<16; off<<=1){ s += __shfl_xor(s,off); d += __shfl_xor(d,off); }
    if ((t & 15)==0 && r < N_NODES){ asrc[r]=s; adst[r]=d; }
  }
}

// ---------------- exclusive scan (3 phase) ----------------
__global__ __launch_bounds__(256) void k_scan_a(const int* __restrict__ deg, int* __restrict__ incl, int* __restrict__ bsum){
  __shared__ int s[256];
  int t = threadIdx.x; int i = blockIdx.x*256 + t;
  int v = (i < N_NODES) ? deg[i] : 0;
  s[t] = v; __syncthreads();
  for (int off=1; off<256; off<<=1){
    int u = (t>=off)? s[t-off] : 0; __syncthreads();
    s[t] += u; __syncthreads();
  }
  if (i < N_NODES) incl[i] = s[t];
  if (t == 255) bsum[blockIdx.x] = s[t];
}
__global__ __launch_bounds__(512) void k_scan_b(const int* __restrict__ bsum, int* __restrict__ bexcl, int nb){
  __shared__ int s[512];
  int t = threadIdx.x;
  int v = (t<nb)? bsum[t] : 0;
  s[t] = v; __syncthreads();
  for (int off=1; off<512; off<<=1){
    int u = (t>=off)? s[t-off] : 0; __syncthreads();
    s[t] += u; __syncthreads();
  }
  if (t<nb) bexcl[t] = s[t]-v;
}
__global__ __launch_bounds__(256) void k_scan_c(const int* __restrict__ incl, const int* __restrict__ deg,
    const int* __restrict__ bexcl, int* __restrict__ rowptr){
  int i = blockIdx.x*256+threadIdx.x;
  if (i < N_NODES) rowptr[i] = incl[i] - deg[i] + bexcl[blockIdx.x];
  if (i == 0) rowptr[N_NODES] = N_EDGES;
}

// ---------------- CSR fill: pure gather -> scatter ----------------
__global__ __launch_bounds__(256) void k_fillf(const int* __restrict__ src, const int* __restrict__ dst,
     const int* __restrict__ rank, const float2* __restrict__ ae01,
     const int* __restrict__ rowptr, uint4* __restrict__ csr){
  int e = blockIdx.x*256+threadIdx.x;
  if (e >= N_EDGES) return;
  int d = dst[e];
  float2 ae = ae01[e];
  int pos = rowptr[d] + rank[e];
  csr[pos] = make_uint4((unsigned)src[e], __float_as_uint(ae.x), __float_as_uint(ae.y), 0u);
}

// ---------------- fp32 GEMM + fused attention dots (layer 1) ----------------
__global__ __launch_bounds__(256) void k_gemm(const float* __restrict__ X, const float* __restrict__ W,
    const float* __restrict__ bias, float* __restrict__ Y, unsigned short* __restrict__ Ybf,
    const float* __restrict__ a_s, const float* __restrict__ a_d,
    float* __restrict__ asrc, float* __restrict__ adst, int M, int relu){
  __shared__ float Xs[16][68];
  __shared__ float Ws[16][128];
  __shared__ float as_s[128], ad_s[128];
  int t = threadIdx.x;
  if (a_s && t < 128){ as_s[t] = a_s[t]; ad_s[t] = a_d[t]; }
  int row0 = blockIdx.x * 64;
  int tc = t & 15, tr = t >> 4;
  int c0 = tc*8, r0 = tr*4;
  int lr = t >> 2, lc = (t & 3) << 2;
  int wk = t >> 4, wc = (t & 15) * 8;
  float acc[4][8];
  #pragma unroll
  for (int i=0;i<4;i++)
    #pragma unroll
    for (int j=0;j<8;j++) acc[i][j]=0.f;
  int gr = row0 + lr;
  for (int k0=0; k0<128; k0+=16){
    float4 xv = make_float4(0.f,0.f,0.f,0.f);
    if (gr < M) xv = *(const float4*)(X + (size_t)gr*128 + k0 + lc);
    float4 wv0 = *(const float4*)(W + (size_t)(k0+wk)*128 + wc);
    float4 wv1 = *(const float4*)(W + (size_t)(k0+wk)*128 + wc + 4);
    __syncthreads();
    Xs[lc+0][lr]=xv.x; Xs[lc+1][lr]=xv.y; Xs[lc+2][lr]=xv.z; Xs[lc+3][lr]=xv.w;
    *(float4*)&Ws[wk][wc]   = wv0;
    *(float4*)&Ws[wk][wc+4] = wv1;
    __syncthreads();
    #pragma unroll
    for (int kk=0;kk<16;kk++){
      float4 a  = *(const float4*)&Xs[kk][r0];
      float4 b0 = *(const float4*)&Ws[kk][c0];
      float4 b1 = *(const float4*)&Ws[kk][c0+4];
      float av[4] = {a.x,a.y,a.z,a.w};
      float bv[8] = {b0.x,b0.y,b0.z,b0.w,b1.x,b1.y,b1.z,b1.w};
      #pragma unroll
      for (int i=0;i<4;i++)
        #pragma unroll
        for (int j=0;j<8;j++) acc[i][j] += av[i]*bv[j];
    }
  }
  #pragma unroll
  for (int i=0;i<4;i++){
    int r = row0 + r0 + i;
    float v[8];
    #pragma unroll
    for (int j=0;j<8;j++){
      float u = acc[i][j] + (bias ? bias[c0+j] : 0.f);
      v[j] = relu ? fmaxf(u, 0.f) : u;
    }
    if (r < M){
      if (Y){
        *(float4*)(Y + (size_t)r*128 + c0)     = make_float4(v[0],v[1],v[2],v[3]);
        *(float4*)(Y + (size_t)r*128 + c0 + 4) = make_float4(v[4],v[5],v[6],v[7]);
      }
      if (Ybf){
        uint4 pk;
        pk.x = (unsigned)f2bf(v[0]) | ((unsigned)f2bf(v[1])<<16);
        pk.y = (unsigned)f2bf(v[2]) | ((unsigned)f2bf(v[3])<<16);
        pk.z = (unsigned)f2bf(v[4]) | ((unsigned)f2bf(v[5])<<16);
        pk.w = (unsigned)f2bf(v[6]) | ((unsigned)f2bf(v[7])<<16);
        *(uint4*)(Ybf + (size_t)r*128 + c0) = pk;
      }
    }
    if (a_s){
      float s=0.f, d=0.f;
      #pragma unroll
      for (int j=0;j<8;j++){ s += v[j]*as_s[c0+j]; d += v[j]*ad_s[c0+j]; }
      #pragma unroll
      for (int off=1; off<16; off<<=1){ s += __shfl_xor(s,off); d += __shfl_xor(d,off); }
      if ((t & 15)==0 && r < M){ asrc[r]=s; adst[r]=d; }
    }
  }
}

// ---------------- GAT aggregation: wave per node (R9 x2 body) ----------------
// R11's x4 unroll reverted: VGPR 24->36 cost occupancy 77->68% and 2us/dispatch.
__global__ __launch_bounds__(256) void k_agg(const int* __restrict__ rowptr, const uint4* __restrict__ csr,
    const float* __restrict__ asrc, const float* __restrict__ adst,
    const unsigned short* __restrict__ xlbf,
    const float* __restrict__ bias, float* __restrict__ out, int relu, int layer){
  int w = threadIdx.x >> 6;
  int lane = threadIdx.x & 63;
  int n = blockIdx.x * WPB + w;          // grid exact
  __shared__ float2 eb[WPB][MAXDEG];     // {alpha->weight, byteoff bits}
  const char* xbase = (const char*)xlbf; // row = 256 B
  int s0 = rowptr[n], s1 = rowptr[n+1];
  int deg = s1 - s0;
  float adst_n = adst[n];
  // pass A
  float m_edge = -1e30f;
  float sae = 0.f;
  for (int base=0; base<deg; base+=64){
    int i = base + lane;
    float a = -1e30f;
    if (i < deg){
      uint4 p4 = csr[s0 + i];
      int sx = (int)p4.x;
      float ae = __uint_as_float(layer ? p4.z : p4.y);
      float av = lrelu(asrc[sx] + adst_n + ae);
      if (i < MAXDEG) eb[w][i] = make_float2(av, __uint_as_float((unsigned)sx << 8));
      a = av;
      sae += ae;
    }
    for (int off=32; off; off>>=1) a = fmaxf(a, __shfl_xor(a, off));
    m_edge = fmaxf(m_edge, a);
  }
  for (int off=32; off; off>>=1) sae += __shfl_xor(sae, off);
  float aloop_n = sae / fmaxf((float)deg, 1.f);
  float al = lrelu(asrc[n] + adst_n + aloop_n);   // self-loop alpha
  float m = fmaxf(m_edge, al);
  // pass B
  float p = 0.f;
  for (int i=lane; i<deg; i+=64){
    float av;
    if (i < MAXDEG) av = eb[w][i].x;
    else { uint4 p4 = csr[s0+i];
           av = lrelu(asrc[p4.x] + adst_n + __uint_as_float(layer ? p4.z : p4.y)); }
    float ev = __expf(av - m);
    if (i < MAXDEG) eb[w][i].x = ev;
    p += ev;
  }
  for (int off=32; off; off>>=1) p += __shfl_xor(p, off);
  float wl = __expf(al - m);
  float denom = p + wl;
  __syncthreads();
  // pass C
  int g = lane >> 4, cl = lane & 15;
  unsigned clb = (unsigned)(cl << 4);
  float acc[8];
  #pragma unroll
  for (int j=0;j<8;j++) acc[j]=0.f;
  if (g == 0){
    uint4 v = *(const uint4*)(xbase + (((unsigned)n << 8) + clb));
    unsigned int uu[4] = {v.x,v.y,v.z,v.w};
    #pragma unroll
    for (int q=0;q<4;q++){
      acc[2*q]   += wl * __uint_as_float(uu[q] << 16);
      acc[2*q+1] += wl * __uint_as_float(uu[q] & 0xFFFF0000u);
    }
  }
  if (deg <= MAXDEG){
    int dfull = deg & ~7;
    for (int i=0; i<dfull; i+=8){      // unguarded main body
      float2 e0 = eb[w][i+g];
      float2 e1 = eb[w][i+4+g];
      uint4 v0 = *(const uint4*)(xbase + (__float_as_uint(e0.y) + clb));
      uint4 v1 = *(const uint4*)(xbase + (__float_as_uint(e1.y) + clb));
      unsigned int uu0[4] = {v0.x,v0.y,v0.z,v0.w};
      unsigned int uu1[4] = {v1.x,v1.y,v1.z,v1.w};
      #pragma unroll
      for (int q=0;q<4;q++){
        acc[2*q]   += e0.x * __uint_as_float(uu0[q] << 16);
        acc[2*q+1] += e0.x * __uint_as_float(uu0[q] & 0xFFFF0000u);
      }
      #pragma unroll
      for (int q=0;q<4;q++){
        acc[2*q]   += e1.x * __uint_as_float(uu1[q] << 16);
        acc[2*q+1] += e1.x * __uint_as_float(uu1[q] & 0xFFFF0000u);
      }
    }
    for (int i=dfull; i<deg; i+=4){    // guarded tail (<8 edges)
      int idx = i + g;
      float we = 0.f; unsigned off = (unsigned)n << 8;
      if (idx < deg){ float2 e = eb[w][idx]; we = e.x; off = __float_as_uint(e.y); }
      uint4 v = *(const uint4*)(xbase + (off + clb));
      unsigned int uu[4] = {v.x,v.y,v.z,v.w};
      #pragma unroll
      for (int q=0;q<4;q++){
        acc[2*q]   += we * __uint_as_float(uu[q] << 16);
        acc[2*q+1] += we * __uint_as_float(uu[q] & 0xFFFF0000u);
      }
    }
  } else {
    for (int i=0; i<deg; i+=8){
      int idx0 = i + g, idx1 = i + 4 + g;
      int sx0 = n, sx1 = n; float we0 = 0.f, we1 = 0.f;
      if (idx0 < deg){
        if (idx0 < MAXDEG){ float2 e = eb[w][idx0]; we0 = e.x; sx0 = (int)(__float_as_uint(e.y) >> 8); }
        else { uint4 p4 = csr[s0+idx0]; sx0 = (int)p4.x;
               we0 = __expf(lrelu(asrc[sx0] + adst_n + __uint_as_float(layer ? p4.z : p4.y)) - m); }
      }
      if (idx1 < deg){
        if (idx1 < MAXDEG){ float2 e = eb[w][idx1]; we1 = e.x; sx1 = (int)(__float_as_uint(e.y) >> 8); }
        else { uint4 p4 = csr[s0+idx1]; sx1 = (int)p4.x;
               we1 = __expf(lrelu(asrc[sx1] + adst_n + __uint_as_float(layer ? p4.z : p4.y)) - m); }
      }
      uint4 v0 = *(const uint4*)(xbase + (((unsigned)sx0 << 8) + clb));
      uint4 v1 = *(const uint4*)(xbase + (((unsigned)sx1 << 8) + clb));
      unsigned int uu0[4] = {v0.x,v0.y,v0.z,v0.w};
      unsigned int uu1[4] = {v1.x,v1.y,v1.z,v1.w};
      #pragma unroll
      for (int q=0;q<4;q++){
        acc[2*q]   += we0 * __uint_as_float(uu0[q] << 16);
        acc[2*q+1] += we0 * __uint_as_float(uu0[q] & 0xFFFF0000u);
      }
      #pragma unroll
      for (int q=0;q<4;q++){
        acc[2*q]   += we1 * __uint_as_float(uu1[q] << 16);
        acc[2*q+1] += we1 * __uint_as_float(uu1[q] & 0xFFFF0000u);
      }
    }
  }
  #pragma unroll
  for (int j=0;j<8;j++){
    acc[j] += __shfl_xor(acc[j], 16);
    acc[j] += __shfl_xor(acc[j], 32);
  }
  if (lane < 16){
    float inv = 1.f/denom;
    float4 b0 = *(const float4*)(bias + cl*8);
    float4 b1 = *(const float4*)(bias + cl*8 + 4);
    float o[8];
    o[0]=acc[0]*inv+b0.x; o[1]=acc[1]*inv+b0.y; o[2]=acc[2]*inv+b0.z; o[3]=acc[3]*inv+b0.w;
    o[4]=acc[4]*inv+b1.x; o[5]=acc[5]*inv+b1.y; o[6]=acc[6]*inv+b1.z; o[7]=acc[7]*inv+b1.w;
    if (relu){
      #pragma unroll
      for (int j=0;j<8;j++) o[j]=fmaxf(o[j],0.f);
    }
    *(float4*)(out + (size_t)n*128 + cl*8)     = make_float4(o[0],o[1],o[2],o[3]);
    *(float4*)(out + (size_t)n*128 + cl*8 + 4) = make_float4(o[4],o[5],o[6],o[7]);
  }
}

// ---------------- fused MLP: lin1 GEMM -> lin2 -> log_softmax ----------------
__global__ __launch_bounds__(256) void k_mlp(const float* __restrict__ X, const float* __restrict__ W,
    const float* __restrict__ bias, const float* __restrict__ w2, const float* __restrict__ b2,
    float* __restrict__ out, int M){
  __shared__ float Xs[16][68];
  __shared__ float Ws[16][128];
  __shared__ float b2s[16];
  int t = threadIdx.x;
  int row0 = blockIdx.x * 64;
  int tc = t & 15, tr = t >> 4;
  int c0 = tc*8, r0 = tr*4;
  int lr = t >> 2, lc = (t & 3) << 2;
  int wk = t >> 4, wc = (t & 15) * 8;
  float acc[4][8];
  #pragma unroll
  for (int i=0;i<4;i++)
    #pragma unroll
    for (int j=0;j<8;j++) acc[i][j]=0.f;
  int gr = row0 + lr;
  for (int k0=0; k0<128; k0+=16){
    float4 xv = make_float4(0.f,0.f,0.f,0.f);
    if (gr < M) xv = *(const float4*)(X + (size_t)gr*128 + k0 + lc);
    float4 wv0 = *(const float4*)(W + (size_t)(k0+wk)*128 + wc);
    float4 wv1 = *(const float4*)(W + (size_t)(k0+wk)*128 + wc + 4);
    __syncthreads();
    Xs[lc+0][lr]=xv.x; Xs[lc+1][lr]=xv.y; Xs[lc+2][lr]=xv.z; Xs[lc+3][lr]=xv.w;
    *(float4*)&Ws[wk][wc]   = wv0;
    *(float4*)&Ws[wk][wc+4] = wv1;
    __syncthreads();
    #pragma unroll
    for (int kk=0;kk<16;kk++){
      float4 a  = *(const float4*)&Xs[kk][r0];
      float4 b0 = *(const float4*)&Ws[kk][c0];
      float4 b1 = *(const float4*)&Ws[kk][c0+4];
      float av[4] = {a.x,a.y,a.z,a.w};
      float bv[8] = {b0.x,b0.y,b0.z,b0.w,b1.x,b1.y,b1.z,b1.w};
      #pragma unroll
      for (int i=0;i<4;i++)
        #pragma unroll
        for (int j=0;j<8;j++) acc[i][j] += av[i]*bv[j];
    }
  }
  __syncthreads();   // all Ws reads done before restage
  float* wflat = &Ws[0][0];   // w2 restaged here: wflat[col*16 + cls]
  #pragma unroll
  for (int i=0;i<2;i++) ((float4*)wflat)[t + i*256] = ((const float4*)w2)[t + i*256];
  if (t < 16) b2s[t] = b2[t];
  // h = relu(acc + l1b) in registers
  float4 bba = *(const float4*)(bias + c0);
  float4 bbb = *(const float4*)(bias + c0 + 4);
  float bb[8] = {bba.x,bba.y,bba.z,bba.w,bbb.x,bbb.y,bbb.z,bbb.w};
  #pragma unroll
  for (int i=0;i<4;i++)
    #pragma unroll
    for (int j=0;j<8;j++) acc[i][j] = fmaxf(acc[i][j] + bb[j], 0.f);
  __syncthreads();   // w2/b2 staged
  // ring-rotate lin2: conflict-free w2 reads (banks j*16+cls, cls distinct)
  float A0=0.f, A1=0.f, A2=0.f, A3=0.f;
  int sl = (tc+1) & 15;
  #pragma unroll 4
  for (int s=0; s<16; s++){
    int cls = (tc + s) & 15;
    const float* wp = wflat + (size_t)c0*16 + cls;
    float p0=0.f,p1=0.f,p2=0.f,p3=0.f;
    #pragma unroll
    for (int j=0;j<8;j++){
      float wv = wp[j*16];
      p0 += acc[0][j]*wv; p1 += acc[1][j]*wv; p2 += acc[2][j]*wv; p3 += acc[3][j]*wv;
    }
    A0+=p0; A1+=p1; A2+=p2; A3+=p3;
    A0=__shfl(A0,sl,16); A1=__shfl(A1,sl,16); A2=__shfl(A2,sl,16); A3=__shfl(A3,sl,16);
  }
  float A[4] = {A0,A1,A2,A3};
  float bcls = b2s[tc];
  #pragma unroll
  for (int i=0;i<4;i++){
    float v = A[i] + bcls;
    float m = v;
    #pragma unroll
    for (int off=1; off<16; off<<=1) m = fmaxf(m, __shfl_xor(m, off, 16));
    float ex = __expf(v - m);
    float sum = ex;
    #pragma unroll
    for (int off=1; off<16; off<<=1) sum += __shfl_xor(sum, off, 16);
    float lse = m + __logf(sum);
    int r = row0 + r0 + i;
    if (r < M) out[(size_t)r*16 + tc] = v - lse;
  }
}

extern "C" void kernel_launch(void* const* d_in, const int* in_sizes, int n_in,
                              void* d_out, int out_size, void* d_ws, size_t ws_size,
                              hipStream_t stream){
  const float* x    = (const float*)d_in[0];
  const float* eatt = (const float*)d_in[1];
  const float* W0   = (const float*)d_in[2];
  const float* as0  = (const float*)d_in[3];
  const float* ad0  = (const float*)d_in[4];
  const float* We0  = (const float*)d_in[5];
  const float* ae0  = (const float*)d_in[6];
  const float* b0   = (const float*)d_in[7];
  const float* W1   = (const float*)d_in[8];
  const float* as1  = (const float*)d_in[9];
  const float* ad1  = (const float*)d_in[10];
  const float* We1  = (const float*)d_in[11];
  const float* ae1  = (const float*)d_in[12];
  const float* b1   = (const float*)d_in[13];
  const float* l1w  = (const float*)d_in[14];
  const float* l1b  = (const float*)d_in[15];
  const float* l2w  = (const float*)d_in[16];
  const float* l2b  = (const float*)d_in[17];
  const int*   ei   = (const int*)d_in[18];
  const int* srcI = ei;
  const int* dstI = ei + N_EDGES;
  float* out = (float*)d_out;

  char* p = (char*)d_ws;
  auto alloc = [&](size_t bytes)->char*{ char* r = p; p += (bytes + 255) & ~255ull; return r; };
  unsigned short* Abf = (unsigned short*)alloc((size_t)N_NODES*128*2); // bf16 features
  float* B       = (float*)alloc((size_t)N_NODES*128*4);   // aggregation output
  float* asrc    = (float*)alloc((size_t)N_NODES*4);
  float* adst    = (float*)alloc((size_t)N_NODES*4);
  int* deg     = (int*)alloc((size_t)N_NODES*4);
  int* rowptr  = (int*)alloc((size_t)(N_NODES+1)*4);
  uint4* csr   = (uint4*)alloc((size_t)N_EDGES*16);
  int* incl    = (int*)alloc((size_t)N_NODES*4);
  int* bsum    = (int*)alloc(512*4);
  int* bexcl   = (int*)alloc(512*4);
  // R12: k_pre's GEMM role writes Abf concurrently with the deg role, so
  // rank/ae01 both live in the B region (dead until agg0 writes B, after
  // fillf has consumed them).
  char*   Bc   = (char*)B;
  int*    rank = (int*)Bc;                    // 6.4MB
  float2* ae01 = (float2*)(Bc + 6400000);     // 12.8MB, ends at 19.2MB < 51.2MB

  const int NB_E = (N_EDGES+255)/256;   // 6250
  const int NB_N = (N_NODES+255)/256;   // 391
  const int NB_W = N_NODES/WPB;         // 25000 (exact)
  const int NB_G = (N_NODES+63)/64;     // 1563
  const int NB_P = 7815;                // 6252 deg-role (covers 6250) + 1563 gemm-role

  // ---- fused preprocessing + layer-0 GEMM ----
  hipMemsetAsync(deg, 0, (size_t)N_NODES*4, stream);
  k_pre  <<<NB_P,256,0,stream>>>(dstI, eatt, We0, ae0, We1, ae1, deg, rank, ae01,
                                 x, W0, as0, ad0, Abf, asrc, adst);
  k_scan_a<<<NB_N,256,0,stream>>>(deg, incl, bsum);
  k_scan_b<<<1,  512,0,stream>>>(bsum, bexcl, NB_N);
  k_scan_c<<<NB_N,256,0,stream>>>(incl, deg, bexcl, rowptr);
  k_fillf <<<NB_E,256,0,stream>>>(srcI, dstI, rank, ae01, rowptr, csr);

  // ---- layer 0 aggregation (GEMM already done in k_pre) ----
  k_agg  <<<NB_W,256,0,stream>>>(rowptr, csr, asrc, adst, Abf, b0, B, 1, 0);

  // ---- layer 1 ----
  k_gemm <<<NB_G,256,0,stream>>>(B, W1, nullptr, nullptr, Abf, as1, ad1, asrc, adst, N_NODES, 0);
  k_agg  <<<NB_W,256,0,stream>>>(rowptr, csr, asrc, adst, Abf, b1, B, 1, 1);

  // ---- post MLP (lin1 + lin2 + log_softmax fused) ----
  k_mlp  <<<NB_G,256,0,stream>>>(B, l1w, l1b, l2w, l2b, out, N_NODES);
}